// Round 3
// baseline (63.202 us; speedup 1.0000x reference)
//
#include <hip/hip_runtime.h>

constexpr int NB = 32;
constexpr int NPAIR = NB * NB;          // 1024
constexpr int HSIZE = NPAIR + NB;       // 1056 words per block-partial
constexpr int DD = 96, HH = 96, WW = 96;
constexpr int SD = HH * WW;             // 9216
constexpr int SH = WW;                  // 96
constexpr int NVOX = 2 * DD * HH * WW;  // 1769472
constexpr int NCH = NVOX / 4;           // 442368 chunks of 4 voxels
constexpr int CW = WW / 4;              // 24 chunks per row
constexpr int NBLK = NCH / 256;         // 1728: exactly 1 chunk per thread
constexpr int HCOPY = 4;                // privatized LDS hist copies (per 16 lanes)
constexpr int HSTRIDE = 1080;           // 1056+24 pad; 1080%32=24 -> bank rotation
constexpr int RED1 = 54;                // 54*32 = 1728
constexpr int SLICE = NBLK / RED1;      // 32 partials per red1 block

__global__ __launch_bounds__(256) void adj_kernel(const int* __restrict__ tgt,
                                                  unsigned int* __restrict__ ws) {
    __shared__ unsigned int hist[HCOPY * HSTRIDE];
    for (int k = threadIdx.x; k < HCOPY * HSTRIDE; k += 256) hist[k] = 0u;
    __syncthreads();

    const int c  = blockIdx.x * 256 + threadIdx.x;   // grid sized exactly
    const int cw = c % CW;
    const int r  = c / CW;
    const int h  = r % HH;
    const int d  = (r / HH) % DD;    // batch boundary handled by dp guard
    const int v0 = c * 4;

    unsigned int* hp = hist + ((threadIdx.x >> 4) & 3) * HSTRIDE;

    const bool hpv = (h + 1 < HH), hmv = (h > 0), dpv = (d + 1 < DD);
    const bool vL = (cw > 0), vR = (cw < CW - 1);

    int4 Cc = *(const int4*)(tgt + v0);
    int ci[4] = {Cc.x, Cc.y, Cc.z, Cc.w};
    int cR = vR ? tgt[v0 + 4] : 0;

    // neighbor rows for the 13 lexicographically-positive offsets:
    // (0,+1,*), (+1,-1,*), (+1,0,*), (+1,+1,*); plus (0,0,+1) in-row
    bool rowv[4];
    rowv[0] = hpv; rowv[1] = dpv && hmv; rowv[2] = dpv; rowv[3] = dpv && hpv;
    const int roff[4] = {SH, SD - SH, SD, SD + SH};
    int a[4][6];
#pragma unroll
    for (int q = 0; q < 4; q++) {
        if (rowv[q]) {
            const int* p = tgt + v0 + roff[q];
            int4 m = *(const int4*)p;
            a[q][1] = m.x; a[q][2] = m.y; a[q][3] = m.z; a[q][4] = m.w;
            a[q][0] = vL ? p[-1] : 0;
            a[q][5] = vR ? p[4]  : 0;
        }
    }

#pragma unroll
    for (int e = 0; e < 4; e++) {
        unsigned int ib = ((unsigned int)ci[e]) << 5;
        atomicAdd(&hp[NPAIR + ci[e]], 1u);              // center (diag) count
        if (e < 3)       atomicAdd(&hp[ib + ci[e + 1]], 1u);   // (0,0,+1)
        else if (vR)     atomicAdd(&hp[ib + cR], 1u);
#pragma unroll
        for (int q = 0; q < 4; q++) {
            if (rowv[q]) {
                if (e > 0 || vL) atomicAdd(&hp[ib + a[q][e]], 1u);
                atomicAdd(&hp[ib + a[q][e + 1]], 1u);
                if (e < 3 || vR) atomicAdd(&hp[ib + a[q][e + 2]], 1u);
            }
        }
    }
    __syncthreads();

    unsigned int* part = ws + (size_t)blockIdx.x * HSIZE;
    for (int k = threadIdx.x; k < HSIZE; k += 256)
        part[k] = hist[k] + hist[HSTRIDE + k] + hist[2 * HSTRIDE + k]
                + hist[3 * HSTRIDE + k];
}

// block b: symmetrized sum over its 32 block-partials -> ws2[b][1024]
__global__ __launch_bounds__(256) void red1_kernel(const unsigned int* __restrict__ ws,
                                                   unsigned int* __restrict__ ws2) {
    const unsigned int* base = ws + (size_t)blockIdx.x * SLICE * HSIZE;
    for (int k = threadIdx.x; k < NPAIR; k += 256) {
        int i = k >> 5, j = k & 31;
        int kT = (j << 5) | i;
        unsigned int s = 0;
#pragma unroll 4
        for (int p = 0; p < SLICE; ++p) {
            const unsigned int* hh = base + p * HSIZE;
            s += hh[k] + hh[kT];
            if (i == j) s += hh[NPAIR + i];
        }
        ws2[blockIdx.x * NPAIR + k] = s;
    }
}

__global__ void red2_kernel(const unsigned int* __restrict__ ws2,
                            float* __restrict__ out) {
    int k = blockIdx.x * blockDim.x + threadIdx.x;   // 4 blocks x 256
    if (k >= NPAIR) return;
    unsigned int s = 0;
#pragma unroll 6
    for (int b = 0; b < RED1; ++b) s += ws2[b * NPAIR + k];
    out[k] = (float)s;
}

extern "C" void kernel_launch(void* const* d_in, const int* in_sizes, int n_in,
                              void* d_out, int out_size, void* d_ws, size_t ws_size,
                              hipStream_t stream) {
    const int* tgt = (const int*)d_in[0];
    float* out = (float*)d_out;
    unsigned int* ws = (unsigned int*)d_ws;
    unsigned int* ws2 = ws + (size_t)NBLK * HSIZE;   // +54*1024 words, ~7.5 MB total

    adj_kernel<<<NBLK, 256, 0, stream>>>(tgt, ws);
    red1_kernel<<<RED1, 256, 0, stream>>>(ws, ws2);
    red2_kernel<<<4, 256, 0, stream>>>(ws2, out);
}

// Round 4
// 23.917 us; speedup vs baseline: 2.6426x; 2.6426x over previous
//
#include <hip/hip_runtime.h>

constexpr int NB = 32;
constexpr int NPAIR = NB * NB;          // 1024
constexpr int HSIZE = NPAIR + NB;       // 1056 words per partial
constexpr int DD = 96, HH = 96, WW = 96;
constexpr int SD = HH * WW;             // 9216
constexpr int SH = WW;                  // 96
constexpr int NVOX = 2 * DD * HH * WW;  // 1769472
constexpr int NCH = NVOX / 4;           // 442368 chunks of 4 voxels
constexpr int CW = WW / 4;              // 24 chunks per row
constexpr int NBLK = NCH / 256;         // 1728: exactly 1 chunk per thread
constexpr int HCOPY = 4;                // privatized LDS hist copies
constexpr int HSTRIDE = 1080;           // 1056+24 pad -> bank rotation per copy
constexpr int NPART = 64;               // global partial histograms

__global__ void zero_kernel(unsigned int* ws, int n) {
    int t = blockIdx.x * blockDim.x + threadIdx.x;
    if (t < n) ws[t] = 0u;
}

__global__ __launch_bounds__(256) void adj_kernel(const int* __restrict__ tgt,
                                                  unsigned int* __restrict__ ws) {
    __shared__ unsigned int hist[HCOPY * HSTRIDE];
    for (int k = threadIdx.x; k < HCOPY * HSTRIDE; k += 256) hist[k] = 0u;
    __syncthreads();

    const int c  = blockIdx.x * 256 + threadIdx.x;   // grid sized exactly
    const int cw = c % CW;
    const int r  = c / CW;
    const int h  = r % HH;
    const int d  = (r / HH) % DD;    // batch boundary handled by dp guard
    const int v0 = c * 4;

    unsigned int* hp = hist + ((threadIdx.x >> 4) & 3) * HSTRIDE;

    const bool hpv = (h + 1 < HH), hmv = (h > 0), dpv = (d + 1 < DD);
    const bool vL = (cw > 0), vR = (cw < CW - 1);

    int4 Cc = *(const int4*)(tgt + v0);
    int ci[4] = {Cc.x, Cc.y, Cc.z, Cc.w};
    int cR = vR ? tgt[v0 + 4] : 0;

    // neighbor rows for the 13 lexicographically-positive offsets:
    // (0,+1,*), (+1,-1,*), (+1,0,*), (+1,+1,*); plus (0,0,+1) in-row
    bool rowv[4];
    rowv[0] = hpv; rowv[1] = dpv && hmv; rowv[2] = dpv; rowv[3] = dpv && hpv;
    const int roff[4] = {SH, SD - SH, SD, SD + SH};
    int a[4][6];
#pragma unroll
    for (int q = 0; q < 4; q++) {
        if (rowv[q]) {
            const int* p = tgt + v0 + roff[q];
            int4 m = *(const int4*)p;
            a[q][1] = m.x; a[q][2] = m.y; a[q][3] = m.z; a[q][4] = m.w;
            a[q][0] = vL ? p[-1] : 0;
            a[q][5] = vR ? p[4]  : 0;
        }
    }

#pragma unroll
    for (int e = 0; e < 4; e++) {
        unsigned int ib = ((unsigned int)ci[e]) << 5;
        atomicAdd(&hp[NPAIR + ci[e]], 1u);              // center (diag) count
        if (e < 3)       atomicAdd(&hp[ib + ci[e + 1]], 1u);   // (0,0,+1)
        else if (vR)     atomicAdd(&hp[ib + cR], 1u);
#pragma unroll
        for (int q = 0; q < 4; q++) {
            if (rowv[q]) {
                if (e > 0 || vL) atomicAdd(&hp[ib + a[q][e]], 1u);
                atomicAdd(&hp[ib + a[q][e + 1]], 1u);
                if (e < 3 || vR) atomicAdd(&hp[ib + a[q][e + 2]], 1u);
            }
        }
    }
    __syncthreads();

    unsigned int* part = ws + (size_t)(blockIdx.x & (NPART - 1)) * HSIZE;
    for (int k = threadIdx.x; k < HSIZE; k += 256) {
        unsigned int val = hist[k] + hist[HSTRIDE + k] + hist[2 * HSTRIDE + k]
                         + hist[3 * HSTRIDE + k];
        if (val) atomicAdd(&part[k], val);
    }
}

// single block, 1024 threads: coalesced sum of 64 partials, then LDS symmetrize
__global__ __launch_bounds__(1024) void final_kernel(const unsigned int* __restrict__ ws,
                                                     float* __restrict__ out) {
    __shared__ unsigned int s[NPAIR];
    __shared__ unsigned int nn[NB];
    const int k = threadIdx.x;
    unsigned int acc = 0;
#pragma unroll 8
    for (int p = 0; p < NPART; ++p) acc += ws[p * HSIZE + k];
    s[k] = acc;
    if (k < NB) {
        unsigned int a2 = 0;
#pragma unroll 8
        for (int p = 0; p < NPART; ++p) a2 += ws[p * HSIZE + NPAIR + k];
        nn[k] = a2;
    }
    __syncthreads();
    const int i = k >> 5, j = k & 31;
    unsigned int v = s[k] + s[(j << 5) | i];
    if (i == j) v += nn[i];
    out[k] = (float)v;
}

extern "C" void kernel_launch(void* const* d_in, const int* in_sizes, int n_in,
                              void* d_out, int out_size, void* d_ws, size_t ws_size,
                              hipStream_t stream) {
    const int* tgt = (const int*)d_in[0];
    float* out = (float*)d_out;
    unsigned int* ws = (unsigned int*)d_ws;

    const int zn = NPART * HSIZE;   // 67584 words
    zero_kernel<<<(zn + 255) / 256, 256, 0, stream>>>(ws, zn);
    adj_kernel<<<NBLK, 256, 0, stream>>>(tgt, ws);
    final_kernel<<<1, 1024, 0, stream>>>(ws, out);
}